// Round 1
// baseline (201.868 us; speedup 1.0000x reference)
//
#include <hip/hip_runtime.h>

#define NTOT 768
#define NHALF 384
#define DDIM 64
#define NPER 200
#define PPAD 256
#define NKER 4
#define GROWS 16
#define CHUNK 192

constexpr int K0SZ  = NTOT * NTOT;
constexpr int OF_K0 = 0;
constexpr int OF_SQ = OF_K0 + NKER * K0SZ;
constexpr int OF_RS0 = OF_SQ + NTOT;
constexpr int OF_RSX = OF_RS0 + NKER * NTOT;
constexpr int OF_RSY = OF_RSX + NKER * NTOT;
constexpr int OF_C   = OF_RSY + NKER * NTOT;
constexpr int OF_ROWM = OF_C + NKER * NHALF;
constexpr int OF_COLM = OF_ROWM + NKER * NTOT;
constexpr int OF_SCAL = OF_COLM + NKER * NTOT;
constexpr int OF_ST   = OF_SCAL + 16;
constexpr int OF_Q0   = OF_ST + NTOT * PPAD;
constexpr int WS_FLOATS = OF_Q0 + NKER * PPAD;  // ~2.57M floats = 10.3 MB

// ---------------- kernel 1: squared norms of Z rows ----------------
__global__ void k_sqnorm(const float* __restrict__ X, const float* __restrict__ Y,
                         float* __restrict__ ws) {
    int a = blockIdx.x * blockDim.x + threadIdx.x;
    if (a >= NTOT) return;
    const float* z = (a < NHALF) ? X + a * DDIM : Y + (a - NHALF) * DDIM;
    float s = 0.f;
#pragma unroll
    for (int d = 0; d < DDIM; ++d) s = fmaf(z[d], z[d], s);
    ws[OF_SQ + a] = s;
}

// ---------------- kernel 2: K0 matrices + per-row block sums ----------------
__global__ void k_matrix(const float* __restrict__ X, const float* __restrict__ Y,
                         const float* __restrict__ bw, float* __restrict__ ws) {
    __shared__ float zb[CHUNK * 65];  // padded stride 65: conflict-free
    __shared__ float red[256];
    int a = blockIdx.x;
    int tid = threadIdx.x;
    const float* za = (a < NHALF) ? X + a * DDIM : Y + (a - NHALF) * DDIM;  // wave-uniform
    float bwv[NKER];
#pragma unroll
    for (int k = 0; k < NKER; ++k) bwv[k] = bw[k];
    float sqa = ws[OF_SQ + a];
    float accX[NKER] = {0.f, 0.f, 0.f, 0.f};
    float accY[NKER] = {0.f, 0.f, 0.f, 0.f};

    for (int c0 = 0; c0 < NTOT; c0 += CHUNK) {
        __syncthreads();
        // stage Z rows [c0, c0+CHUNK) into LDS, coalesced
        for (int idx = tid; idx < CHUNK * DDIM; idx += 256) {
            int r = idx >> 6, d = idx & 63;
            int gr = c0 + r;
            const float* zr = (gr < NHALF) ? X + gr * DDIM : Y + (gr - NHALF) * DDIM;
            zb[r * 65 + d] = zr[d];
        }
        __syncthreads();
        if (tid < CHUNK) {
            int b = c0 + tid;
            float dot = 0.f;
#pragma unroll
            for (int d = 0; d < DDIM; ++d) dot = fmaf(za[d], zb[tid * 65 + d], dot);
            float d2 = (sqa + ws[OF_SQ + b]) - 2.f * dot;
            if (b == a) d2 = 0.f;       // exact diagonal
            d2 = fmaxf(d2, 0.f);
            float dist = sqrtf(d2 + 1e-12f);
            float dist2 = dist * dist;
#pragma unroll
            for (int k = 0; k < NKER; ++k) {
                float bb = bwv[k];
                float val = ((k & 1) == 0) ? expf(-dist2 / (bb * bb)) : expf(-dist / bb);
                ws[OF_K0 + k * K0SZ + a * NTOT + b] = val;
                if (b < NHALF) accX[k] += val; else accY[k] += val;
                if (a < NHALF && b == a + NHALF) ws[OF_C + k * NHALF + a] = val;
            }
        }
    }
    // block-reduce the 8 partial sums
#pragma unroll
    for (int k = 0; k < NKER; ++k) {
        __syncthreads(); red[tid] = accX[k]; __syncthreads();
        for (int s = 128; s > 0; s >>= 1) { if (tid < s) red[tid] += red[tid + s]; __syncthreads(); }
        float sx = red[0];
        __syncthreads(); red[tid] = accY[k]; __syncthreads();
        for (int s = 128; s > 0; s >>= 1) { if (tid < s) red[tid] += red[tid + s]; __syncthreads(); }
        if (tid == 0) {
            float sy = red[0];
            ws[OF_RS0 + k * NTOT + a] = sx + sy;
            ws[OF_RSX + k * NTOT + a] = sx;
            ws[OF_RSY + k * NTOT + a] = sy;
        }
        __syncthreads();
    }
}

// ---------------- kernel 3: totals, rowM/colM, U statistics ----------------
__device__ float blk_reduce256(float v, float* sred, int tid) {
    sred[tid] = v; __syncthreads();
    for (int s = 128; s > 0; s >>= 1) { if (tid < s) sred[tid] += sred[tid + s]; __syncthreads(); }
    float r = sred[0]; __syncthreads();
    return r;
}

__global__ void k_final(const float* __restrict__ bw, float* __restrict__ ws,
                        float* __restrict__ out) {
    __shared__ float sred[256];
    int tid = threadIdx.x;
    for (int k = 0; k < NKER; ++k) {
        float v;
        v = 0.f; for (int a = tid; a < NTOT;  a += 256) v += ws[OF_RS0 + k * NTOT + a];
        float tot0 = blk_reduce256(v, sred, tid);
        v = 0.f; for (int a = tid; a < NHALF; a += 256) v += ws[OF_C + k * NHALF + a];
        float csum = blk_reduce256(v, sred, tid);
        v = 0.f; for (int a = tid; a < NHALF; a += 256) v += ws[OF_RSX + k * NTOT + a];
        float sxx = blk_reduce256(v, sred, tid);
        v = 0.f; for (int a = tid; a < NHALF; a += 256) v += ws[OF_RSY + k * NTOT + NHALF + a];
        float syy = blk_reduce256(v, sred, tid);
        v = 0.f; for (int a = tid; a < NHALF; a += 256) v += ws[OF_RSY + k * NTOT + a];
        float sxy = blk_reduce256(v, sred, tid);
        if (tid == 0) {
            float b = bw[k];
            float dist0 = sqrtf(1e-12f);
            float dk = ((k & 1) == 0) ? expf(-(dist0 * dist0) / (b * b)) : expf(-dist0 / b);
            ws[OF_SCAL + k * 4 + 0] = tot0 - csum;  // total of modified K
            ws[OF_SCAL + k * 4 + 1] = dk;           // diagonal value
            double U = ((double)sxx - 384.0 * (double)dk) * (1.0 / 147072.0)
                     + ((double)syy - 384.0 * (double)dk) * (1.0 / 147072.0)
                     - 2.0 * ((double)sxy - (double)csum) * (1.0 / 147456.0);
            out[k * 201] = (float)U;
        }
        __syncthreads();
    }
    // rowM/colM of the modified (zeroed) K
    for (int idx = tid; idx < NTOT; idx += 256) {
#pragma unroll
        for (int k = 0; k < NKER; ++k) {
            float r0 = ws[OF_RS0 + k * NTOT + idx];
            float cx = (idx < NHALF)  ? ws[OF_C + k * NHALF + idx] : 0.f;
            float cy = (idx >= NHALF) ? ws[OF_C + k * NHALF + idx - NHALF] : 0.f;
            ws[OF_ROWM + k * NTOT + idx] = r0 - cx;
            ws[OF_COLM + k * NTOT + idx] = r0 - cy;
        }
    }
}

// ---------------- kernel 4: scatter permutation membership S^T (768 x 256) ----------------
__global__ void k_scatter(const int* __restrict__ perms, float* __restrict__ ws) {
    int p = blockIdx.x, i = threadIdx.x;  // i < 384
    int v = perms[p * NTOT + i];
    ws[OF_ST + v * PPAD + p] = 1.f;
}

// ---------------- kernel 5: q0[p] = s^T K0 s via register-blocked GEMM ----------------
__global__ void k_gemm(float* ws) {
    int k  = blockIdx.z;
    int a0 = blockIdx.x * GROWS;
    int b0 = blockIdx.y * (NTOT / 2);
    int p  = threadIdx.x;
    const float* K0k = ws + OF_K0 + k * K0SZ;
    const float* ST  = ws + OF_ST;
    float t[GROWS];
#pragma unroll
    for (int j = 0; j < GROWS; ++j) t[j] = 0.f;
#pragma unroll 2
    for (int b = b0; b < b0 + NTOT / 2; ++b) {
        float sv = ST[b * PPAD + p];                 // coalesced vector load
        const float* kr = K0k + b * NTOT + a0;       // symmetric: K0[a0+j][b], wave-uniform s_load
#pragma unroll
        for (int j = 0; j < GROWS; ++j) t[j] = fmaf(kr[j], sv, t[j]);
    }
    float q = 0.f;
#pragma unroll
    for (int j = 0; j < GROWS; ++j) q += ST[(a0 + j) * PPAD + p] * t[j];
    atomicAdd(ws + OF_Q0 + k * PPAD + p, q);
}

// ---------------- kernel 6: per-permutation gathered sums + final U_b ----------------
__global__ void k_perm(const int* __restrict__ perms, const float* __restrict__ ws,
                       float* __restrict__ out) {
    int p = blockIdx.x, k = blockIdx.y, i = threadIdx.x;  // blockDim = 512
    float rsv = 0.f, csv = 0.f, pairv = 0.f, qcv = 0.f;
    if (i < NHALF) {
        int a  = perms[p * NTOT + i];
        int bY = perms[p * NTOT + NHALF + i];
        rsv = ws[OF_ROWM + k * NTOT + a];
        csv = ws[OF_COLM + k * NTOT + a];
        float kv = ws[OF_K0 + k * K0SZ + a * NTOT + bY];
        if (a < NHALF && bY == a + NHALF) kv = 0.f;  // zeroed entry
        pairv = kv;
        qcv = ws[OF_C + k * NHALF + i] * ws[OF_ST + i * PPAD + p]
                                       * ws[OF_ST + (i + NHALF) * PPAD + p];
    }
    __shared__ float4 red[512];
    red[i] = make_float4(rsv, csv, pairv, qcv);
    __syncthreads();
    for (int s = 256; s > 0; s >>= 1) {
        if (i < s) {
            float4 o = red[i + s]; float4 m = red[i];
            m.x += o.x; m.y += o.y; m.z += o.z; m.w += o.w;
            red[i] = m;
        }
        __syncthreads();
    }
    if (i == 0) {
        float4 r = red[0];
        double rs = r.x, cs = r.y, pair = r.z, qc = r.w;
        double total_mod = (double)ws[OF_SCAL + k * 4 + 0];
        double dk        = (double)ws[OF_SCAL + k * 4 + 1];
        double q   = (double)ws[OF_Q0 + k * PPAD + p] - qc;
        double sXX = q - 384.0 * dk;
        double sYY = total_mod - rs - cs + q - 384.0 * dk;
        double sXY = rs - q - pair;
        out[k * 201 + 1 + p] =
            (float)(sXX * (1.0 / 147072.0) + sYY * (1.0 / 147072.0) - 2.0 * sXY * (1.0 / 147456.0));
    }
}

extern "C" void kernel_launch(void* const* d_in, const int* in_sizes, int n_in,
                              void* d_out, int out_size, void* d_ws, size_t ws_size,
                              hipStream_t stream) {
    const float* X     = (const float*)d_in[0];
    const float* Y     = (const float*)d_in[1];
    const float* bw    = (const float*)d_in[2];
    const int*   perms = (const int*)d_in[3];
    float* ws  = (float*)d_ws;
    float* out = (float*)d_out;

    // zero S^T + q0 accumulators (contiguous region)
    hipMemsetAsync(ws + OF_ST, 0, (size_t)(NTOT * PPAD + NKER * PPAD) * sizeof(float), stream);

    k_sqnorm <<<3, 256, 0, stream>>>(X, Y, ws);
    k_matrix <<<NTOT, 256, 0, stream>>>(X, Y, bw, ws);
    k_final  <<<1, 256, 0, stream>>>(bw, ws, out);
    k_scatter<<<NPER, NHALF, 0, stream>>>(perms, ws);
    k_gemm   <<<dim3(NTOT / GROWS, 2, NKER), PPAD, 0, stream>>>(ws);
    k_perm   <<<dim3(NPER, NKER), 512, 0, stream>>>(perms, ws, out);
}

// Round 2
// 146.998 us; speedup vs baseline: 1.3733x; 1.3733x over previous
//
#include <hip/hip_runtime.h>

#define NTOT 768
#define NHALF 384
#define DDIM 64
#define NPER 200
#define PPAD 256
#define NKER 4
#define GROWS 16
#define BCHUNK 96
#define CHUNK 192

constexpr int K0SZ  = NTOT * NTOT;
constexpr int OF_K0 = 0;
constexpr int OF_SQ = OF_K0 + NKER * K0SZ;
constexpr int OF_RS0 = OF_SQ + NTOT;
constexpr int OF_RSX = OF_RS0 + NKER * NTOT;
constexpr int OF_RSY = OF_RSX + NKER * NTOT;
constexpr int OF_C   = OF_RSY + NKER * NTOT;
constexpr int OF_ROWM = OF_C + NKER * NHALF;
constexpr int OF_COLM = OF_ROWM + NKER * NTOT;
constexpr int OF_SCAL = OF_COLM + NKER * NTOT;
constexpr int OF_ST   = OF_SCAL + 16;
constexpr int OF_Q0   = OF_ST + NTOT * PPAD;
constexpr int WS_FLOATS = OF_Q0 + NKER * PPAD;  // ~2.57M floats = 10.3 MB

// ---------------- kernel 1: squared norms of Z rows ----------------
__global__ void k_sqnorm(const float* __restrict__ X, const float* __restrict__ Y,
                         float* __restrict__ ws) {
    int a = blockIdx.x * blockDim.x + threadIdx.x;
    if (a >= NTOT) return;
    const float* z = (a < NHALF) ? X + a * DDIM : Y + (a - NHALF) * DDIM;
    float s = 0.f;
#pragma unroll
    for (int d = 0; d < DDIM; ++d) s = fmaf(z[d], z[d], s);
    ws[OF_SQ + a] = s;
}

// ---------------- kernel 2: K0 matrices + per-row block sums ----------------
__global__ void k_matrix(const float* __restrict__ X, const float* __restrict__ Y,
                         const float* __restrict__ bw, float* __restrict__ ws) {
    __shared__ float zb[CHUNK * 65];   // padded stride 65: 2-way max (free)
    __shared__ float zaS[DDIM];
    __shared__ float redw[4 * 8];
    int a = blockIdx.x;
    int tid = threadIdx.x;
    const float* za = (a < NHALF) ? X + a * DDIM : Y + (a - NHALF) * DDIM;  // wave-uniform
    if (tid < DDIM) zaS[tid] = za[tid];
    float bwv[NKER];
#pragma unroll
    for (int k = 0; k < NKER; ++k) bwv[k] = bw[k];
    float sqa = ws[OF_SQ + a];
    float accX[NKER] = {0.f, 0.f, 0.f, 0.f};
    float accY[NKER] = {0.f, 0.f, 0.f, 0.f};

    for (int c0 = 0; c0 < NTOT; c0 += CHUNK) {
        __syncthreads();
        for (int idx = tid; idx < CHUNK * DDIM; idx += 256) {
            int r = idx >> 6, d = idx & 63;
            int gr = c0 + r;
            const float* zr = (gr < NHALF) ? X + gr * DDIM : Y + (gr - NHALF) * DDIM;
            zb[r * 65 + d] = zr[d];
        }
        __syncthreads();
        if (tid < CHUNK) {
            int b = c0 + tid;
            float dot = 0.f;
#pragma unroll
            for (int d = 0; d < DDIM; ++d) dot = fmaf(zaS[d], zb[tid * 65 + d], dot);
            float d2 = (sqa + ws[OF_SQ + b]) - 2.f * dot;
            if (b == a) d2 = 0.f;
            d2 = fmaxf(d2, 0.f);
            float dist = sqrtf(d2 + 1e-12f);
            float dist2 = dist * dist;
#pragma unroll
            for (int k = 0; k < NKER; ++k) {
                float bb = bwv[k];
                float val = ((k & 1) == 0) ? expf(-dist2 / (bb * bb)) : expf(-dist / bb);
                ws[OF_K0 + k * K0SZ + a * NTOT + b] = val;
                if (b < NHALF) accX[k] += val; else accY[k] += val;
                if (a < NHALF && b == a + NHALF) ws[OF_C + k * NHALF + a] = val;
            }
        }
    }
    // shuffle-based reduction of 8 partials (replaces 64-barrier LDS tree)
    float vals[8];
#pragma unroll
    for (int k = 0; k < NKER; ++k) { vals[k] = accX[k]; vals[4 + k] = accY[k]; }
#pragma unroll
    for (int off = 32; off > 0; off >>= 1)
#pragma unroll
        for (int v = 0; v < 8; ++v) vals[v] += __shfl_down(vals[v], off, 64);
    int wid = tid >> 6, lane = tid & 63;
    if (lane == 0)
#pragma unroll
        for (int v = 0; v < 8; ++v) redw[wid * 8 + v] = vals[v];
    __syncthreads();
    if (tid == 0) {
#pragma unroll
        for (int k = 0; k < NKER; ++k) {
            float sx = redw[k] + redw[8 + k] + redw[16 + k] + redw[24 + k];
            float sy = redw[4 + k] + redw[12 + k] + redw[20 + k] + redw[28 + k];
            ws[OF_RS0 + k * NTOT + a] = sx + sy;
            ws[OF_RSX + k * NTOT + a] = sx;
            ws[OF_RSY + k * NTOT + a] = sy;
        }
    }
}

// ---------------- kernel 3: totals + U statistic + rowM/colM (one block per k) --------
__global__ void k_final(const float* __restrict__ bw, float* __restrict__ ws,
                        float* __restrict__ out) {
    __shared__ float redw[4 * 8];
    int k = blockIdx.x;
    int tid = threadIdx.x;
    float v[5] = {0.f, 0.f, 0.f, 0.f, 0.f};
    for (int a = tid; a < NTOT; a += 256) v[0] += ws[OF_RS0 + k * NTOT + a];
    for (int a = tid; a < NHALF; a += 256) {
        v[1] += ws[OF_C + k * NHALF + a];
        v[2] += ws[OF_RSX + k * NTOT + a];
        v[3] += ws[OF_RSY + k * NTOT + NHALF + a];
        v[4] += ws[OF_RSY + k * NTOT + a];
    }
#pragma unroll
    for (int off = 32; off > 0; off >>= 1)
#pragma unroll
        for (int j = 0; j < 5; ++j) v[j] += __shfl_down(v[j], off, 64);
    int wid = tid >> 6, lane = tid & 63;
    if (lane == 0)
#pragma unroll
        for (int j = 0; j < 5; ++j) redw[wid * 8 + j] = v[j];
    __syncthreads();
    if (tid == 0) {
        float tot0 = redw[0] + redw[8] + redw[16] + redw[24];
        float csum = redw[1] + redw[9] + redw[17] + redw[25];
        float sxx  = redw[2] + redw[10] + redw[18] + redw[26];
        float syy  = redw[3] + redw[11] + redw[19] + redw[27];
        float sxy  = redw[4] + redw[12] + redw[20] + redw[28];
        float b = bw[k];
        float dist0 = sqrtf(1e-12f);
        float dk = ((k & 1) == 0) ? expf(-(dist0 * dist0) / (b * b)) : expf(-dist0 / b);
        ws[OF_SCAL + k * 4 + 0] = tot0 - csum;
        ws[OF_SCAL + k * 4 + 1] = dk;
        double U = ((double)sxx - 384.0 * (double)dk) * (1.0 / 147072.0)
                 + ((double)syy - 384.0 * (double)dk) * (1.0 / 147072.0)
                 - 2.0 * ((double)sxy - (double)csum) * (1.0 / 147456.0);
        out[k * 201] = (float)U;
    }
    for (int idx = tid; idx < NTOT; idx += 256) {
        float r0 = ws[OF_RS0 + k * NTOT + idx];
        float cx = (idx < NHALF)  ? ws[OF_C + k * NHALF + idx] : 0.f;
        float cy = (idx >= NHALF) ? ws[OF_C + k * NHALF + idx - NHALF] : 0.f;
        ws[OF_ROWM + k * NTOT + idx] = r0 - cx;
        ws[OF_COLM + k * NTOT + idx] = r0 - cy;
    }
}

// ---------------- kernel 4: scatter permutation membership S^T (768 x 256) ----------------
__global__ void k_scatter(const int* __restrict__ perms, float* __restrict__ ws) {
    int p = blockIdx.x, i = threadIdx.x;  // i < 384
    int v = perms[p * NTOT + i];
    ws[OF_ST + v * PPAD + p] = 1.f;
}

// ---------------- kernel 5: q0[p] partials, 8-way b-split for occupancy ----------------
__global__ __launch_bounds__(256) void k_gemm(const float* __restrict__ K0,
                                              const float* __restrict__ ST,
                                              float* __restrict__ q0) {
    int k  = blockIdx.z;
    int a0 = blockIdx.x * GROWS;
    int b0 = blockIdx.y * BCHUNK;
    int p  = threadIdx.x;
    const float* Kk = K0 + k * K0SZ;
    float t[GROWS];
#pragma unroll
    for (int j = 0; j < GROWS; ++j) t[j] = 0.f;
#pragma unroll 2
    for (int b = b0; b < b0 + BCHUNK; ++b) {
        float sv = ST[b * PPAD + p];                       // coalesced, L2-resident
        const float4* kr = (const float4*)(Kk + b * NTOT + a0);  // block-uniform
        float4 k0 = kr[0], k1 = kr[1], k2 = kr[2], k3 = kr[3];
        t[0]  = fmaf(k0.x, sv, t[0]);  t[1]  = fmaf(k0.y, sv, t[1]);
        t[2]  = fmaf(k0.z, sv, t[2]);  t[3]  = fmaf(k0.w, sv, t[3]);
        t[4]  = fmaf(k1.x, sv, t[4]);  t[5]  = fmaf(k1.y, sv, t[5]);
        t[6]  = fmaf(k1.z, sv, t[6]);  t[7]  = fmaf(k1.w, sv, t[7]);
        t[8]  = fmaf(k2.x, sv, t[8]);  t[9]  = fmaf(k2.y, sv, t[9]);
        t[10] = fmaf(k2.z, sv, t[10]); t[11] = fmaf(k2.w, sv, t[11]);
        t[12] = fmaf(k3.x, sv, t[12]); t[13] = fmaf(k3.y, sv, t[13]);
        t[14] = fmaf(k3.z, sv, t[14]); t[15] = fmaf(k3.w, sv, t[15]);
    }
    float q = 0.f;
#pragma unroll
    for (int j = 0; j < GROWS; ++j) q += ST[(a0 + j) * PPAD + p] * t[j];
    atomicAdd(q0 + k * PPAD + p, q);
}

// ---------------- kernel 6: per-permutation gathered sums + final U_b ----------------
__global__ void k_perm(const int* __restrict__ perms, const float* __restrict__ ws,
                       float* __restrict__ out) {
    int p = blockIdx.x, k = blockIdx.y, i = threadIdx.x;  // blockDim = 512
    float v0 = 0.f, v1 = 0.f, v2 = 0.f, v3 = 0.f;
    if (i < NHALF) {
        int a  = perms[p * NTOT + i];
        int bY = perms[p * NTOT + NHALF + i];
        v0 = ws[OF_ROWM + k * NTOT + a];
        v1 = ws[OF_COLM + k * NTOT + a];
        float kv = ws[OF_K0 + k * K0SZ + a * NTOT + bY];
        if (a < NHALF && bY == a + NHALF) kv = 0.f;
        v2 = kv;
        v3 = ws[OF_C + k * NHALF + i] * ws[OF_ST + i * PPAD + p]
                                      * ws[OF_ST + (i + NHALF) * PPAD + p];
    }
#pragma unroll
    for (int off = 32; off > 0; off >>= 1) {
        v0 += __shfl_down(v0, off, 64);
        v1 += __shfl_down(v1, off, 64);
        v2 += __shfl_down(v2, off, 64);
        v3 += __shfl_down(v3, off, 64);
    }
    __shared__ float4 rw[8];
    if ((i & 63) == 0) rw[i >> 6] = make_float4(v0, v1, v2, v3);
    __syncthreads();
    if (i == 0) {
        float rs = 0.f, cs = 0.f, pair = 0.f, qc = 0.f;
#pragma unroll
        for (int w = 0; w < 8; ++w) {
            rs += rw[w].x; cs += rw[w].y; pair += rw[w].z; qc += rw[w].w;
        }
        double total_mod = (double)ws[OF_SCAL + k * 4 + 0];
        double dk        = (double)ws[OF_SCAL + k * 4 + 1];
        double q   = (double)ws[OF_Q0 + k * PPAD + p] - (double)qc;
        double sXX = q - 384.0 * dk;
        double sYY = total_mod - (double)rs - (double)cs + q - 384.0 * dk;
        double sXY = (double)rs - q - (double)pair;
        out[k * 201 + 1 + p] =
            (float)(sXX * (1.0 / 147072.0) + sYY * (1.0 / 147072.0) - 2.0 * sXY * (1.0 / 147456.0));
    }
}

extern "C" void kernel_launch(void* const* d_in, const int* in_sizes, int n_in,
                              void* d_out, int out_size, void* d_ws, size_t ws_size,
                              hipStream_t stream) {
    const float* X     = (const float*)d_in[0];
    const float* Y     = (const float*)d_in[1];
    const float* bw    = (const float*)d_in[2];
    const int*   perms = (const int*)d_in[3];
    float* ws  = (float*)d_ws;
    float* out = (float*)d_out;

    hipMemsetAsync(ws + OF_ST, 0, (size_t)(NTOT * PPAD + NKER * PPAD) * sizeof(float), stream);

    k_sqnorm <<<3, 256, 0, stream>>>(X, Y, ws);
    k_matrix <<<NTOT, 256, 0, stream>>>(X, Y, bw, ws);
    k_final  <<<NKER, 256, 0, stream>>>(bw, ws, out);
    k_scatter<<<NPER, NHALF, 0, stream>>>(perms, ws);
    k_gemm   <<<dim3(NTOT / GROWS, NTOT / BCHUNK, NKER), PPAD, 0, stream>>>(
                 ws + OF_K0, ws + OF_ST, ws + OF_Q0);
    k_perm   <<<dim3(NPER, NKER), 512, 0, stream>>>(perms, ws, out);
}

// Round 3
// 120.131 us; speedup vs baseline: 1.6804x; 1.2236x over previous
//
#include <hip/hip_runtime.h>

#define NTOT 768
#define NHALF 384
#define DDIM 64
#define NPER 200
#define PPAD 256
#define NKER 4
#define CHUNK 192

typedef __attribute__((ext_vector_type(8))) short short8;    // 8 bf16 (4 VGPR)
typedef __attribute__((ext_vector_type(4))) float floatx4;   // MFMA acc

constexpr int K0SZ  = NTOT * NTOT;
constexpr int OF_K0 = 0;                                  // fp32 K [4][768][768]
constexpr int OF_KH = OF_K0 + NKER * K0SZ;                // bf16 K (ushort), same extent
constexpr int KH_FLOATS = NKER * K0SZ / 2;
constexpr int OF_SQ  = OF_KH + KH_FLOATS;
constexpr int OF_RS0 = OF_SQ + NTOT;
constexpr int OF_RSX = OF_RS0 + NKER * NTOT;
constexpr int OF_RSY = OF_RSX + NKER * NTOT;
constexpr int OF_C   = OF_RSY + NKER * NTOT;
constexpr int OF_ROWM = OF_C + NKER * NHALF;
constexpr int OF_COLM = OF_ROWM + NKER * NTOT;
constexpr int OF_SCAL = OF_COLM + NKER * NTOT;
constexpr int OF_STT  = OF_SCAL + 16;                     // bf16 S^T [PPAD][NTOT]
constexpr int STT_FLOATS = PPAD * NTOT / 2;
constexpr int OF_Q0   = OF_STT + STT_FLOATS;              // fp32 [4][PPAD]

__device__ __forceinline__ unsigned short f2bf(float f) {  // RTN, no truncation bias
    unsigned int u = __float_as_uint(f);
    return (unsigned short)((u + 0x7FFFu + ((u >> 16) & 1u)) >> 16);
}
__device__ __forceinline__ float bf2f(unsigned short h) {
    return __uint_as_float(((unsigned int)h) << 16);
}

// ---------------- kernel 1: squared norms of Z rows ----------------
__global__ void k_sqnorm(const float* __restrict__ X, const float* __restrict__ Y,
                         float* __restrict__ ws) {
    int a = blockIdx.x * blockDim.x + threadIdx.x;
    if (a >= NTOT) return;
    const float* z = (a < NHALF) ? X + a * DDIM : Y + (a - NHALF) * DDIM;
    float s = 0.f;
#pragma unroll
    for (int d = 0; d < DDIM; ++d) s = fmaf(z[d], z[d], s);
    ws[OF_SQ + a] = s;
}

// ---------------- kernel 2: K0 fp32 + bf16 copy + per-row block sums ----------------
__global__ void k_matrix(const float* __restrict__ X, const float* __restrict__ Y,
                         const float* __restrict__ bw, float* __restrict__ ws) {
    __shared__ float zb[CHUNK * 65];
    __shared__ float zaS[DDIM];
    __shared__ float redw[4 * 8];
    int a = blockIdx.x;
    int tid = threadIdx.x;
    unsigned short* KH = (unsigned short*)(ws + OF_KH);
    const float* za = (a < NHALF) ? X + a * DDIM : Y + (a - NHALF) * DDIM;
    if (tid < DDIM) zaS[tid] = za[tid];
    float ib2[NKER], ib1[NKER];
#pragma unroll
    for (int k = 0; k < NKER; ++k) { float b = bw[k]; ib2[k] = 1.f / (b * b); ib1[k] = 1.f / b; }
    float sqa = ws[OF_SQ + a];
    float accX[NKER] = {0.f, 0.f, 0.f, 0.f};
    float accY[NKER] = {0.f, 0.f, 0.f, 0.f};

    for (int c0 = 0; c0 < NTOT; c0 += CHUNK) {
        __syncthreads();
        for (int idx = tid; idx < CHUNK * DDIM; idx += 256) {
            int r = idx >> 6, d = idx & 63;
            int gr = c0 + r;
            const float* zr = (gr < NHALF) ? X + gr * DDIM : Y + (gr - NHALF) * DDIM;
            zb[r * 65 + d] = zr[d];
        }
        __syncthreads();
        if (tid < CHUNK) {
            int b = c0 + tid;
            float dot = 0.f;
#pragma unroll
            for (int d = 0; d < DDIM; ++d) dot = fmaf(zaS[d], zb[tid * 65 + d], dot);
            float d2 = (sqa + ws[OF_SQ + b]) - 2.f * dot;
            if (b == a) d2 = 0.f;
            d2 = fmaxf(d2, 0.f);
            float d2e = d2 + 1e-12f;
            float dist = sqrtf(d2e);
#pragma unroll
            for (int k = 0; k < NKER; ++k) {
                float val = ((k & 1) == 0) ? __expf(-d2e * ib2[k]) : __expf(-dist * ib1[k]);
                ws[OF_K0 + k * K0SZ + a * NTOT + b] = val;
                KH[k * K0SZ + a * NTOT + b] = f2bf(val);
                if (b < NHALF) accX[k] += val; else accY[k] += val;
                if (a < NHALF && b == a + NHALF) ws[OF_C + k * NHALF + a] = val;
            }
        }
    }
    float vals[8];
#pragma unroll
    for (int k = 0; k < NKER; ++k) { vals[k] = accX[k]; vals[4 + k] = accY[k]; }
#pragma unroll
    for (int off = 32; off > 0; off >>= 1)
#pragma unroll
        for (int v = 0; v < 8; ++v) vals[v] += __shfl_down(vals[v], off, 64);
    int wid = tid >> 6, lane = tid & 63;
    if (lane == 0)
#pragma unroll
        for (int v = 0; v < 8; ++v) redw[wid * 8 + v] = vals[v];
    __syncthreads();
    if (tid == 0) {
#pragma unroll
        for (int k = 0; k < NKER; ++k) {
            float sx = redw[k] + redw[8 + k] + redw[16 + k] + redw[24 + k];
            float sy = redw[4 + k] + redw[12 + k] + redw[20 + k] + redw[28 + k];
            ws[OF_RS0 + k * NTOT + a] = sx + sy;
            ws[OF_RSX + k * NTOT + a] = sx;
            ws[OF_RSY + k * NTOT + a] = sy;
        }
    }
}

// ---------------- kernel 3: totals + U statistic + rowM/colM (one block per k) --------
__global__ void k_final(const float* __restrict__ bw, float* __restrict__ ws,
                        float* __restrict__ out) {
    __shared__ float redw[4 * 8];
    int k = blockIdx.x;
    int tid = threadIdx.x;
    float v[5] = {0.f, 0.f, 0.f, 0.f, 0.f};
    for (int a = tid; a < NTOT; a += 256) v[0] += ws[OF_RS0 + k * NTOT + a];
    for (int a = tid; a < NHALF; a += 256) {
        v[1] += ws[OF_C + k * NHALF + a];
        v[2] += ws[OF_RSX + k * NTOT + a];
        v[3] += ws[OF_RSY + k * NTOT + NHALF + a];
        v[4] += ws[OF_RSY + k * NTOT + a];
    }
#pragma unroll
    for (int off = 32; off > 0; off >>= 1)
#pragma unroll
        for (int j = 0; j < 5; ++j) v[j] += __shfl_down(v[j], off, 64);
    int wid = tid >> 6, lane = tid & 63;
    if (lane == 0)
#pragma unroll
        for (int j = 0; j < 5; ++j) redw[wid * 8 + j] = v[j];
    __syncthreads();
    if (tid == 0) {
        float tot0 = redw[0] + redw[8] + redw[16] + redw[24];
        float csum = redw[1] + redw[9] + redw[17] + redw[25];
        float sxx  = redw[2] + redw[10] + redw[18] + redw[26];
        float syy  = redw[3] + redw[11] + redw[19] + redw[27];
        float sxy  = redw[4] + redw[12] + redw[20] + redw[28];
        float b = bw[k];
        float dist0 = sqrtf(1e-12f);
        float dk = ((k & 1) == 0) ? expf(-(dist0 * dist0) / (b * b)) : expf(-dist0 / b);
        ws[OF_SCAL + k * 4 + 0] = tot0 - csum;
        ws[OF_SCAL + k * 4 + 1] = dk;
        double U = ((double)sxx - 384.0 * (double)dk) * (1.0 / 147072.0)
                 + ((double)syy - 384.0 * (double)dk) * (1.0 / 147072.0)
                 - 2.0 * ((double)sxy - (double)csum) * (1.0 / 147456.0);
        out[k * 201] = (float)U;
    }
    for (int idx = tid; idx < NTOT; idx += 256) {
        float r0 = ws[OF_RS0 + k * NTOT + idx];
        float cx = (idx < NHALF)  ? ws[OF_C + k * NHALF + idx] : 0.f;
        float cy = (idx >= NHALF) ? ws[OF_C + k * NHALF + idx - NHALF] : 0.f;
        ws[OF_ROWM + k * NTOT + idx] = r0 - cx;
        ws[OF_COLM + k * NTOT + idx] = r0 - cy;
    }
}

// ---------------- kernel 4: scatter S^T (bf16, [perm][index], transposed) ----------------
__global__ void k_scatter(const int* __restrict__ perms, float* __restrict__ ws) {
    int p = blockIdx.x, i = threadIdx.x;  // i < 384
    unsigned short* STT = (unsigned short*)(ws + OF_STT);
    int v = perms[p * NTOT + i];
    STT[p * NTOT + v] = 0x3F80;  // bf16 1.0
}

// ---------------- kernel 5: q0 via MFMA — T = K·S, fused ⊙S column-reduce ----------------
// wave tile: 16(m=a) × 16(n=perm); A[m=lane&15][k=quad*8+j]; B[k=quad*8+j][n=lane&15];
// D: col=lane&15, row=quad*4+reg (m89-verified)
__global__ __launch_bounds__(256) void k_gemm(const unsigned short* __restrict__ KH,
                                              const unsigned short* __restrict__ STT,
                                              float* __restrict__ q0) {
    int k = blockIdx.z;
    int wave = threadIdx.x >> 6;
    int lane = threadIdx.x & 63;
    int m0 = (blockIdx.x * 4 + wave) * 16;   // a-tile base (48 m-tiles)
    int n0 = blockIdx.y * 16;                // perm-tile base (16 n-tiles)
    int row = lane & 15, quad = lane >> 4;
    const unsigned short* A = KH + (size_t)k * K0SZ;
    const unsigned short* aptr = A + (m0 + row) * NTOT + quad * 8;
    const unsigned short* bptr = STT + (n0 + row) * NTOT + quad * 8;
    floatx4 acc0 = {0.f, 0.f, 0.f, 0.f};
    floatx4 acc1 = {0.f, 0.f, 0.f, 0.f};
    for (int kk = 0; kk < NTOT; kk += 64) {
        short8 a0 = *(const short8*)(aptr + kk);
        short8 b0 = *(const short8*)(bptr + kk);
        short8 a1 = *(const short8*)(aptr + kk + 32);
        short8 b1 = *(const short8*)(bptr + kk + 32);
        acc0 = __builtin_amdgcn_mfma_f32_16x16x32_bf16(a0, b0, acc0, 0, 0, 0);
        acc1 = __builtin_amdgcn_mfma_f32_16x16x32_bf16(a1, b1, acc1, 0, 0, 0);
    }
    // epilogue: part[n] = sum_m T[m][n] * S[m][n];  S[m][n] = STT[n][m]
    const unsigned short* sptr = STT + (n0 + row) * NTOT + m0 + quad * 4;
    float part = 0.f;
#pragma unroll
    for (int r = 0; r < 4; ++r) part += (acc0[r] + acc1[r]) * bf2f(sptr[r]);
    part += __shfl_down(part, 32, 64);
    part += __shfl_down(part, 16, 64);
    if (lane < 16) atomicAdd(q0 + k * PPAD + n0 + lane, part);
}

// ---------------- kernel 6: per-permutation gathered sums + final U_b ----------------
__global__ __launch_bounds__(384) void k_perm(const int* __restrict__ perms,
                                              const float* __restrict__ ws,
                                              float* __restrict__ out) {
    int p = blockIdx.x, i = threadIdx.x;  // 384 threads, all 4 kernels per block
    const unsigned short* STT = (const unsigned short*)(ws + OF_STT);
    int a  = perms[p * NTOT + i];
    int bY = perms[p * NTOT + NHALF + i];
    float si  = bf2f(STT[p * NTOT + i]);
    float si2 = bf2f(STT[p * NTOT + NHALF + i]);
    float v[16];  // [k][rs, cs, pair, qc]
#pragma unroll
    for (int k = 0; k < NKER; ++k) {
        v[k * 4 + 0] = ws[OF_ROWM + k * NTOT + a];
        v[k * 4 + 1] = ws[OF_COLM + k * NTOT + a];
        float kv = ws[OF_K0 + k * K0SZ + a * NTOT + bY];
        if (a < NHALF && bY == a + NHALF) kv = 0.f;
        v[k * 4 + 2] = kv;
        v[k * 4 + 3] = ws[OF_C + k * NHALF + i] * si * si2;
    }
#pragma unroll
    for (int off = 32; off > 0; off >>= 1)
#pragma unroll
        for (int j = 0; j < 16; ++j) v[j] += __shfl_down(v[j], off, 64);
    __shared__ float redw[6 * 16];
    int wid = i >> 6, lane = i & 63;
    if (lane == 0)
#pragma unroll
        for (int j = 0; j < 16; ++j) redw[wid * 16 + j] = v[j];
    __syncthreads();
    if (i < 16) {
        float s = 0.f;
#pragma unroll
        for (int w = 0; w < 6; ++w) s += redw[w * 16 + i];
        redw[i] = s;
    }
    __syncthreads();
    if (i < NKER) {
        int k = i;
        double rs = redw[k * 4 + 0], cs = redw[k * 4 + 1];
        double pair = redw[k * 4 + 2], qc = redw[k * 4 + 3];
        double total_mod = (double)ws[OF_SCAL + k * 4 + 0];
        double dk        = (double)ws[OF_SCAL + k * 4 + 1];
        double q   = (double)ws[OF_Q0 + k * PPAD + p] - qc;
        double sXX = q - 384.0 * dk;
        double sYY = total_mod - rs - cs + q - 384.0 * dk;
        double sXY = rs - q - pair;
        out[k * 201 + 1 + p] =
            (float)(sXX * (1.0 / 147072.0) + sYY * (1.0 / 147072.0) - 2.0 * sXY * (1.0 / 147456.0));
    }
}

extern "C" void kernel_launch(void* const* d_in, const int* in_sizes, int n_in,
                              void* d_out, int out_size, void* d_ws, size_t ws_size,
                              hipStream_t stream) {
    const float* X     = (const float*)d_in[0];
    const float* Y     = (const float*)d_in[1];
    const float* bw    = (const float*)d_in[2];
    const int*   perms = (const int*)d_in[3];
    float* ws  = (float*)d_ws;
    float* out = (float*)d_out;

    // zero S^T (bf16) + q0 accumulators (contiguous)
    hipMemsetAsync(ws + OF_STT, 0, (size_t)(STT_FLOATS + NKER * PPAD) * sizeof(float), stream);

    k_sqnorm <<<3, 256, 0, stream>>>(X, Y, ws);
    k_matrix <<<NTOT, 256, 0, stream>>>(X, Y, bw, ws);
    k_final  <<<NKER, 256, 0, stream>>>(bw, ws, out);
    k_scatter<<<NPER, NHALF, 0, stream>>>(perms, ws);
    k_gemm   <<<dim3(12, 16, NKER), 256, 0, stream>>>(
                 (const unsigned short*)(ws + OF_KH),
                 (const unsigned short*)(ws + OF_STT), ws + OF_Q0);
    k_perm   <<<NPER, 384, 0, stream>>>(perms, ws, out);
}

// Round 4
// 107.091 us; speedup vs baseline: 1.8850x; 1.1218x over previous
//
#include <hip/hip_runtime.h>

#define NTOT 768
#define NHALF 384
#define DDIM 64
#define NPER 200
#define PPAD 256
#define NKER 4
#define CHUNK 192
#define NMB 12   // m-blocks of 64 rows
#define NNC 8    // n-chunks of 32 perms

typedef __attribute__((ext_vector_type(8))) short short8;    // 8 bf16 (4 VGPR)
typedef __attribute__((ext_vector_type(4))) float floatx4;   // MFMA acc

constexpr int K0SZ  = NTOT * NTOT;
constexpr int OF_KH = 0;                                  // bf16 K [4][768][768] (ushort)
constexpr int KH_FLOATS = NKER * K0SZ / 2;
constexpr int OF_RS0 = OF_KH + KH_FLOATS;
constexpr int OF_RSX = OF_RS0 + NKER * NTOT;
constexpr int OF_RSY = OF_RSX + NKER * NTOT;
constexpr int OF_C   = OF_RSY + NKER * NTOT;
constexpr int OF_ROWM = OF_C + NKER * NHALF;
constexpr int OF_COLM = OF_ROWM + NKER * NTOT;
constexpr int OF_SCAL = OF_COLM + NKER * NTOT;
constexpr int OF_STT  = OF_SCAL + 16;                     // bf16 S^T [PPAD][NTOT]
constexpr int STT_FLOATS = PPAD * NTOT / 2;
constexpr int OF_Q0P  = OF_STT + STT_FLOATS;              // fp32 [4][NMB][PPAD] partials

__device__ __forceinline__ unsigned short f2bf(float f) {  // RTN
    unsigned int u = __float_as_uint(f);
    return (unsigned short)((u + 0x7FFFu + ((u >> 16) & 1u)) >> 16);
}
__device__ __forceinline__ float bf2f(unsigned short h) {
    return __uint_as_float(((unsigned int)h) << 16);
}

// ============ stage 1: [scatter STT] + [K matrix + row sums], one dispatch ============
// blocks 0..199: zero+scatter STT row p (and zero pad row 200+p for p<56)
// blocks 200..967: K row a = bid-200 for all 4 kernels (self-contained norms)
__global__ __launch_bounds__(256) void k_stage1(const float* __restrict__ X,
                                                const float* __restrict__ Y,
                                                const float* __restrict__ bw,
                                                const int* __restrict__ perms,
                                                float* __restrict__ ws) {
    __shared__ float zb[CHUNK * 65];
    __shared__ float zaS[DDIM];
    __shared__ float redw[32];
    int bid = blockIdx.x, tid = threadIdx.x;
    unsigned short* STT = (unsigned short*)(ws + OF_STT);

    if (bid < NPER) {
        // zero STT row bid (768 ushorts = 192 uint2), and pad row 200+bid
        if (tid < 192) {
            ((uint2*)(STT + bid * NTOT))[tid] = make_uint2(0u, 0u);
            if (bid < PPAD - NPER)
                ((uint2*)(STT + (NPER + bid) * NTOT))[tid] = make_uint2(0u, 0u);
        }
        __syncthreads();
        int v = perms[bid * NTOT + tid];
        STT[bid * NTOT + v] = 0x3F80;  // bf16 1.0
        if (tid < NHALF - 256) {
            int v2 = perms[bid * NTOT + 256 + tid];
            STT[bid * NTOT + v2] = 0x3F80;
        }
        return;
    }

    int a = bid - NPER;
    unsigned short* KH = (unsigned short*)(ws + OF_KH);
    const float* za = (a < NHALF) ? X + a * DDIM : Y + (a - NHALF) * DDIM;
    if (tid < DDIM) zaS[tid] = za[tid];
    float ib2[NKER], ib1[NKER];
#pragma unroll
    for (int k = 0; k < NKER; ++k) { float b = bw[k]; ib2[k] = 1.f / (b * b); ib1[k] = 1.f / b; }
    __syncthreads();
    float sqa = 0.f;
#pragma unroll
    for (int d = 0; d < DDIM; ++d) sqa = fmaf(zaS[d], zaS[d], sqa);

    float accX[NKER] = {0.f, 0.f, 0.f, 0.f};
    float accY[NKER] = {0.f, 0.f, 0.f, 0.f};

    for (int c0 = 0; c0 < NTOT; c0 += CHUNK) {
        __syncthreads();
        for (int idx = tid; idx < CHUNK * DDIM; idx += 256) {
            int r = idx >> 6, d = idx & 63;
            int gr = c0 + r;
            const float* zr = (gr < NHALF) ? X + gr * DDIM : Y + (gr - NHALF) * DDIM;
            zb[r * 65 + d] = zr[d];
        }
        __syncthreads();
        if (tid < CHUNK) {
            int b = c0 + tid;
            float dot = 0.f, sqb = 0.f;
#pragma unroll
            for (int d = 0; d < DDIM; ++d) {
                float zv = zb[tid * 65 + d];
                dot = fmaf(zaS[d], zv, dot);
                sqb = fmaf(zv, zv, sqb);
            }
            float d2 = (sqa + sqb) - 2.f * dot;
            if (b == a) d2 = 0.f;
            d2 = fmaxf(d2, 0.f);
            float d2e = d2 + 1e-12f;
            float dist = sqrtf(d2e);
#pragma unroll
            for (int k = 0; k < NKER; ++k) {
                float val = ((k & 1) == 0) ? __expf(-d2e * ib2[k]) : __expf(-dist * ib1[k]);
                KH[k * K0SZ + a * NTOT + b] = f2bf(val);
                if (b < NHALF) accX[k] += val; else accY[k] += val;
                if (a < NHALF && b == a + NHALF) ws[OF_C + k * NHALF + a] = val;
            }
        }
    }
    float vals[8];
#pragma unroll
    for (int k = 0; k < NKER; ++k) { vals[k] = accX[k]; vals[4 + k] = accY[k]; }
#pragma unroll
    for (int off = 32; off > 0; off >>= 1)
#pragma unroll
        for (int v = 0; v < 8; ++v) vals[v] += __shfl_down(vals[v], off, 64);
    int wid = tid >> 6, lane = tid & 63;
    if (lane == 0)
#pragma unroll
        for (int v = 0; v < 8; ++v) redw[wid * 8 + v] = vals[v];
    __syncthreads();
    if (tid == 0) {
#pragma unroll
        for (int k = 0; k < NKER; ++k) {
            float sx = redw[k] + redw[8 + k] + redw[16 + k] + redw[24 + k];
            float sy = redw[4 + k] + redw[12 + k] + redw[20 + k] + redw[28 + k];
            ws[OF_RS0 + k * NTOT + a] = sx + sy;
            ws[OF_RSX + k * NTOT + a] = sx;
            ws[OF_RSY + k * NTOT + a] = sy;
        }
    }
}

// ============ stage 2: [MFMA gemm partials] + [totals/U/rowM/colM], one dispatch ============
// blocks 0..383: gemm tile (mb, nc, k); blocks 384..387: final for k = bid-384
__global__ __launch_bounds__(256) void k_stage2(const float* __restrict__ bw,
                                                float* __restrict__ ws,
                                                float* __restrict__ out) {
    __shared__ float shred[128];
    int bid = blockIdx.x, tid = threadIdx.x;

    if (bid < NMB * NNC * NKER) {
        int mb = bid % NMB;
        int t  = bid / NMB;
        int nc = t % NNC;
        int k  = t / NNC;
        int wave = tid >> 6, lane = tid & 63;
        int m0 = mb * 64 + wave * 16;
        int n0 = nc * 32;
        int row = lane & 15, quad = lane >> 4;
        const unsigned short* KH  = (const unsigned short*)(ws + OF_KH);
        const unsigned short* STT = (const unsigned short*)(ws + OF_STT);
        const unsigned short* aptr = KH + k * K0SZ + (m0 + row) * NTOT + quad * 8;
        const unsigned short* b0p  = STT + (n0 + row) * NTOT + quad * 8;
        const unsigned short* b1p  = STT + (n0 + 16 + row) * NTOT + quad * 8;
        floatx4 acc00 = {0.f,0.f,0.f,0.f}, acc01 = {0.f,0.f,0.f,0.f};
        floatx4 acc10 = {0.f,0.f,0.f,0.f}, acc11 = {0.f,0.f,0.f,0.f};
        for (int kk = 0; kk < NTOT; kk += 64) {
            short8 a0  = *(const short8*)(aptr + kk);
            short8 a1  = *(const short8*)(aptr + kk + 32);
            short8 b00 = *(const short8*)(b0p + kk);
            short8 b01 = *(const short8*)(b0p + kk + 32);
            short8 b10 = *(const short8*)(b1p + kk);
            short8 b11 = *(const short8*)(b1p + kk + 32);
            acc00 = __builtin_amdgcn_mfma_f32_16x16x32_bf16(a0, b00, acc00, 0, 0, 0);
            acc01 = __builtin_amdgcn_mfma_f32_16x16x32_bf16(a1, b01, acc01, 0, 0, 0);
            acc10 = __builtin_amdgcn_mfma_f32_16x16x32_bf16(a0, b10, acc10, 0, 0, 0);
            acc11 = __builtin_amdgcn_mfma_f32_16x16x32_bf16(a1, b11, acc11, 0, 0, 0);
        }
        // epilogue: part[n] = sum_m T[m][n]*S[m][n];  D layout col=lane&15,row=quad*4+r
        const unsigned short* s0 = STT + (n0 + row) * NTOT + m0 + quad * 4;
        const unsigned short* s1 = STT + (n0 + 16 + row) * NTOT + m0 + quad * 4;
        float p0 = 0.f, p1 = 0.f;
#pragma unroll
        for (int r = 0; r < 4; ++r) {
            p0 += (acc00[r] + acc01[r]) * bf2f(s0[r]);
            p1 += (acc10[r] + acc11[r]) * bf2f(s1[r]);
        }
        p0 += __shfl_down(p0, 32, 64); p0 += __shfl_down(p0, 16, 64);
        p1 += __shfl_down(p1, 32, 64); p1 += __shfl_down(p1, 16, 64);
        if (lane < 16) { shred[wave * 32 + lane] = p0; shred[wave * 32 + 16 + lane] = p1; }
        __syncthreads();
        if (tid < 32) {
            float s = shred[tid] + shred[32 + tid] + shred[64 + tid] + shred[96 + tid];
            ws[OF_Q0P + (k * NMB + mb) * PPAD + n0 + tid] = s;
        }
        return;
    }

    int k = bid - NMB * NNC * NKER;
    float v[5] = {0.f, 0.f, 0.f, 0.f, 0.f};
    for (int a = tid; a < NTOT; a += 256) v[0] += ws[OF_RS0 + k * NTOT + a];
    for (int a = tid; a < NHALF; a += 256) {
        v[1] += ws[OF_C + k * NHALF + a];
        v[2] += ws[OF_RSX + k * NTOT + a];
        v[3] += ws[OF_RSY + k * NTOT + NHALF + a];
        v[4] += ws[OF_RSY + k * NTOT + a];
    }
#pragma unroll
    for (int off = 32; off > 0; off >>= 1)
#pragma unroll
        for (int j = 0; j < 5; ++j) v[j] += __shfl_down(v[j], off, 64);
    int wid = tid >> 6, lane = tid & 63;
    if (lane == 0)
#pragma unroll
        for (int j = 0; j < 5; ++j) shred[wid * 8 + j] = v[j];
    __syncthreads();
    if (tid == 0) {
        float tot0 = shred[0] + shred[8] + shred[16] + shred[24];
        float csum = shred[1] + shred[9] + shred[17] + shred[25];
        float sxx  = shred[2] + shred[10] + shred[18] + shred[26];
        float syy  = shred[3] + shred[11] + shred[19] + shred[27];
        float sxy  = shred[4] + shred[12] + shred[20] + shred[28];
        float b = bw[k];
        float dist0 = sqrtf(1e-12f);
        float dk = ((k & 1) == 0) ? expf(-(dist0 * dist0) / (b * b)) : expf(-dist0 / b);
        ws[OF_SCAL + k * 4 + 0] = tot0 - csum;
        ws[OF_SCAL + k * 4 + 1] = dk;
        double U = ((double)sxx - 384.0 * (double)dk) * (1.0 / 147072.0)
                 + ((double)syy - 384.0 * (double)dk) * (1.0 / 147072.0)
                 - 2.0 * ((double)sxy - (double)csum) * (1.0 / 147456.0);
        out[k * 201] = (float)U;
    }
    for (int idx = tid; idx < NTOT; idx += 256) {
        float r0 = ws[OF_RS0 + k * NTOT + idx];
        float cx = (idx < NHALF)  ? ws[OF_C + k * NHALF + idx] : 0.f;
        float cy = (idx >= NHALF) ? ws[OF_C + k * NHALF + idx - NHALF] : 0.f;
        ws[OF_ROWM + k * NTOT + idx] = r0 - cx;
        ws[OF_COLM + k * NTOT + idx] = r0 - cy;
    }
}

// ============ stage 3: per-permutation gathered sums + final U_b ============
__global__ __launch_bounds__(384) void k_perm(const int* __restrict__ perms,
                                              const float* __restrict__ ws,
                                              float* __restrict__ out) {
    int p = blockIdx.x, i = threadIdx.x;  // 384 threads, all 4 kernels per block
    const unsigned short* STT = (const unsigned short*)(ws + OF_STT);
    const unsigned short* KH  = (const unsigned short*)(ws + OF_KH);
    int a  = perms[p * NTOT + i];
    int bY = perms[p * NTOT + NHALF + i];
    float si  = bf2f(STT[p * NTOT + i]);
    float si2 = bf2f(STT[p * NTOT + NHALF + i]);
    float v[16];  // [k][rs, cs, pair, qc]
#pragma unroll
    for (int k = 0; k < NKER; ++k) {
        v[k * 4 + 0] = ws[OF_ROWM + k * NTOT + a];
        v[k * 4 + 1] = ws[OF_COLM + k * NTOT + a];
        float kv = bf2f(KH[k * K0SZ + a * NTOT + bY]);
        if (a < NHALF && bY == a + NHALF) kv = 0.f;
        v[k * 4 + 2] = kv;
        v[k * 4 + 3] = ws[OF_C + k * NHALF + i] * si * si2;
    }
#pragma unroll
    for (int off = 32; off > 0; off >>= 1)
#pragma unroll
        for (int j = 0; j < 16; ++j) v[j] += __shfl_down(v[j], off, 64);
    __shared__ float redw[6 * 16];
    int wid = i >> 6, lane = i & 63;
    if (lane == 0)
#pragma unroll
        for (int j = 0; j < 16; ++j) redw[wid * 16 + j] = v[j];
    __syncthreads();
    if (i < 16) {
        float s = 0.f;
#pragma unroll
        for (int w = 0; w < 6; ++w) s += redw[w * 16 + i];
        redw[i] = s;
    }
    __syncthreads();
    if (i < NKER) {
        int k = i;
        double rs = redw[k * 4 + 0], cs = redw[k * 4 + 1];
        double pair = redw[k * 4 + 2], qc = redw[k * 4 + 3];
        double total_mod = (double)ws[OF_SCAL + k * 4 + 0];
        double dk        = (double)ws[OF_SCAL + k * 4 + 1];
        double q = -qc;
#pragma unroll
        for (int mb = 0; mb < NMB; ++mb) q += (double)ws[OF_Q0P + (k * NMB + mb) * PPAD + p];
        double sXX = q - 384.0 * dk;
        double sYY = total_mod - rs - cs + q - 384.0 * dk;
        double sXY = rs - q - pair;
        out[k * 201 + 1 + p] =
            (float)(sXX * (1.0 / 147072.0) + sYY * (1.0 / 147072.0) - 2.0 * sXY * (1.0 / 147456.0));
    }
}

extern "C" void kernel_launch(void* const* d_in, const int* in_sizes, int n_in,
                              void* d_out, int out_size, void* d_ws, size_t ws_size,
                              hipStream_t stream) {
    const float* X     = (const float*)d_in[0];
    const float* Y     = (const float*)d_in[1];
    const float* bw    = (const float*)d_in[2];
    const int*   perms = (const int*)d_in[3];
    float* ws  = (float*)d_ws;
    float* out = (float*)d_out;

    k_stage1<<<NPER + NTOT, 256, 0, stream>>>(X, Y, bw, perms, ws);
    k_stage2<<<NMB * NNC * NKER + NKER, 256, 0, stream>>>(bw, ws, out);
    k_perm  <<<NPER, 384, 0, stream>>>(perms, ws, out);
}